// Round 3
// baseline (262.451 us; speedup 1.0000x reference)
//
#include <hip/hip_runtime.h>

// EnhancedReconstructionLoss: loss = 0.8*mean((x-y)^2) + 0.2*(1 - mean(ssim_map))
// ssim from 3x3 avg pools (stride 1, zero-pad 1, divisor always 9).
// Shapes: (32,3,512,512) fp32 -> 96 planes of 512x512.
//
// R2: atomics -> per-block partial stores (639 -> 101 us main).
// R3: parallel 2-stage reduce; rcp not divide (96 us).
// R4: 64x64 f32 LDS tile, 4x4/thread (91 us).
// R6: f16 LDS staging (19 KB/block). 89 us, VALUBusy 43%, HBM 28%.
// R8 FAILED: agent-scope ACQ_REL finish -> 372 us (serialized cache-maint RMWs).
// R9 ~NEUTRAL (87 us): async split was dead on arrival -- loads issued BEFORE
//     __syncthreads get drained by its vmcnt(0) (m97 barrier-drain). Counters
//     prove stage/compute phases serialize: 30 us mem + 41 us VALU ~= 87 us.
// R10 (this): structural overlap, no prefetch ever crosses a barrier:
//     - persistent blocks: grid 8x8x32 = 2048 (exactly resident), 3 planes each
//     - LDS regions A (rows 0..33) and B (rows 32..65, rows 32/33 duplicated,
//       +3% fetch) -> passA/passB read disjoint regions; writes to one region
//       need no barrier vs reads of the other
//     - per tile: writeA(waits pf) | bar | issue-B-pf | passA | writeB | bar |
//       issue-nextA-pf | passB.  Every barrier sees vmcnt==0; every prefetch
//       flies under a full compute pass.
//     - holds: uniform 2 float4 per array per thread (16 VGPR, A/B lifetimes
//       disjoint); 100-quad tails loaded inline at write time.

#define PLANE_H 512
#define PLANE_W 512
#define NPLANES 96
#define TILE    64
#define LDSW    72                  // halfs/row; 144 B stride
#define RROWS   34                  // rows per region
#define RQUADS  (RROWS * 18)        // 612 quads per region
#define PFQ     512                 // prefetched quads (2/thread uniform)
#define NBLOCKS ((PLANE_W / TILE) * (PLANE_H / TILE) * (NPLANES / 3))  // 2048
#define NB1     (NBLOCKS / 256)     // 8

typedef __fp16 half_t;
typedef __fp16 half2_t __attribute__((ext_vector_type(2)));
typedef __fp16 half4_t __attribute__((ext_vector_type(4)));

static constexpr float kC1s  = 81.0f * 0.0001f;   // 81*C1
static constexpr float kC2s  = 81.0f * 0.0009f;   // 81*C2
static constexpr float kEPSs = 6561.0f * 1e-8f;   // 81^2*eps
static constexpr float kINVN = 1.0f / 25165824.0f;

// cvt f32 quad -> f16 quad + LDS write at [r][4*hq]
__device__ __forceinline__ void stage_write(
    half_t (*sx)[LDSW], half_t (*sy)[LDSW],
    int r, int hq, const float4& vx, const float4& vy)
{
    const half2_t xl = __builtin_amdgcn_cvt_pkrtz(vx.x, vx.y);
    const half2_t xh = __builtin_amdgcn_cvt_pkrtz(vx.z, vx.w);
    const half2_t yl = __builtin_amdgcn_cvt_pkrtz(vy.x, vy.y);
    const half2_t yh = __builtin_amdgcn_cvt_pkrtz(vy.z, vy.w);
    const half4_t x4 = {xl.x, xl.y, xh.x, xh.y};
    const half4_t y4 = {yl.x, yl.y, yh.x, yh.y};
    *(half4_t*)&sx[r][4 * hq] = x4;
    *(half4_t*)&sy[r][4 * hq] = y4;
}

// one region pass: 16 row-groups x 16 col-groups; thread handles 2 rows x 4
// cols. Reads region rows 2rg..2rg+3; outputs centers at region rows
// 2rg+1, 2rg+2 (pixel rows = region_base + 2rg, +1).
__device__ __forceinline__ void ssim_pass(
    const half_t (*sxh)[LDSW], const half_t (*syh)[LDSW],
    const int pr0, const int cb, float& ssim_acc)
{
    // ring[row%3][qty][pair]  qty: 0=x 1=y 2=xx+yy 3=xy  (f16-packed row sums)
    half2_t ring[3][4][2];

#pragma unroll
    for (int j = 0; j < 4; ++j) {
        const int R = pr0 + j;
        const half_t* __restrict__ rx = &sxh[R][0];
        const half_t* __restrict__ ry = &syh[R][0];
        const half2_t ax = *(const half2_t*)&rx[cb + 2];   // b32
        const half4_t bx = *(const half4_t*)&rx[cb + 4];   // b64
        const half2_t cx = *(const half2_t*)&rx[cb + 8];   // b32
        const half2_t ay = *(const half2_t*)&ry[cb + 2];
        const half4_t by = *(const half4_t*)&ry[cb + 4];
        const half2_t cy = *(const half2_t*)&ry[cb + 8];

        const float ex0 = (float)ax.y, ex1 = (float)bx.x, ex2 = (float)bx.y,
                    ex3 = (float)bx.z, ex4 = (float)bx.w, ex5 = (float)cx.x;
        const float ey0 = (float)ay.y, ey1 = (float)by.x, ey2 = (float)by.y,
                    ey3 = (float)by.z, ey4 = (float)by.w, ey5 = (float)cy.x;

        half2_t (&slot)[4][2] = ring[j % 3];   // static after unroll

        {
            const float t12 = ex1 + ex2, t23 = ex2 + ex3, t34 = ex3 + ex4;
            slot[0][0] = __builtin_amdgcn_cvt_pkrtz(ex0 + t12, t12 + ex3);
            slot[0][1] = __builtin_amdgcn_cvt_pkrtz(t23 + ex4, t34 + ex5);
        }
        {
            const float t12 = ey1 + ey2, t23 = ey2 + ey3, t34 = ey3 + ey4;
            slot[1][0] = __builtin_amdgcn_cvt_pkrtz(ey0 + t12, t12 + ey3);
            slot[1][1] = __builtin_amdgcn_cvt_pkrtz(t23 + ey4, t34 + ey5);
        }
        {
            const float s0 = __builtin_fmaf(ex0, ex0, ey0 * ey0);
            const float s1 = __builtin_fmaf(ex1, ex1, ey1 * ey1);
            const float s2 = __builtin_fmaf(ex2, ex2, ey2 * ey2);
            const float s3 = __builtin_fmaf(ex3, ex3, ey3 * ey3);
            const float s4 = __builtin_fmaf(ex4, ex4, ey4 * ey4);
            const float s5 = __builtin_fmaf(ex5, ex5, ey5 * ey5);
            const float t12 = s1 + s2, t23 = s2 + s3, t34 = s3 + s4;
            slot[2][0] = __builtin_amdgcn_cvt_pkrtz(s0 + t12, t12 + s3);
            slot[2][1] = __builtin_amdgcn_cvt_pkrtz(t23 + s4, t34 + s5);
        }
        {
            const float p0 = ex0 * ey0, p1 = ex1 * ey1, p2 = ex2 * ey2;
            const float p3 = ex3 * ey3, p4 = ex4 * ey4, p5 = ex5 * ey5;
            const float t12 = p1 + p2, t23 = p2 + p3, t34 = p3 + p4;
            slot[3][0] = __builtin_amdgcn_cvt_pkrtz(p0 + t12, t12 + p3);
            slot[3][1] = __builtin_amdgcn_cvt_pkrtz(t23 + p4, t34 + p5);
        }

        if (j >= 2) {
            const half2_t sx01 = ring[0][0][0] + ring[1][0][0] + ring[2][0][0];
            const half2_t sx23 = ring[0][0][1] + ring[1][0][1] + ring[2][0][1];
            const half2_t sy01 = ring[0][1][0] + ring[1][1][0] + ring[2][1][0];
            const half2_t sy23 = ring[0][1][1] + ring[1][1][1] + ring[2][1][1];
            const half2_t ss01 = ring[0][2][0] + ring[1][2][0] + ring[2][2][0];
            const half2_t ss23 = ring[0][2][1] + ring[1][2][1] + ring[2][2][1];
            const half2_t sp01 = ring[0][3][0] + ring[1][3][0] + ring[2][3][0];
            const half2_t sp23 = ring[0][3][1] + ring[1][3][1] + ring[2][3][1];

            const float S_x[4] = {(float)sx01.x, (float)sx01.y, (float)sx23.x, (float)sx23.y};
            const float S_y[4] = {(float)sy01.x, (float)sy01.y, (float)sy23.x, (float)sy23.y};
            const float S_s[4] = {(float)ss01.x, (float)ss01.y, (float)ss23.x, (float)ss23.y};
            const float S_p[4] = {(float)sp01.x, (float)sp01.y, (float)sp23.x, (float)sp23.y};

#pragma unroll
            for (int c = 0; c < 4; ++c) {
                // scaled-domain SSIM: window sums x9 (mu x9); 81^2 cancels in
                // num/den; eps scales by 81^2.
                const float P   = S_x[c] * S_y[c];
                const float Q   = __builtin_fmaf(S_x[c], S_x[c], S_y[c] * S_y[c]);
                const float t1  = __builtin_fmaf(2.0f, P, kC1s);
                const float t3  = __builtin_fmaf(18.0f, S_p[c],
                                      __builtin_fmaf(-2.0f, P, kC2s));
                const float num = t1 * t3;
                const float u2  = __builtin_fmaf(9.0f, S_s[c], -Q);  // >= 0 (C-S)
                const float den = __builtin_fmaf(Q + kC1s, u2 + kC2s, kEPSs);
                ssim_acc = __builtin_fmaf(num, __builtin_amdgcn_rcpf(den), ssim_acc);
            }
        }
    }
}

__global__ __launch_bounds__(256, 8) void loss_main(
    const float* __restrict__ X, const float* __restrict__ Y,
    float* __restrict__ part)
{
    // Region A <-> tile rows 0..33 (global tr0-1+r); MSE rows r in [1,33].
    // Region B <-> tile rows 32..65 (global tr0+31+r); MSE rows r in [2,32].
    __shared__ __align__(16) half_t sxA[RROWS][LDSW];
    __shared__ __align__(16) half_t syA[RROWS][LDSW];
    __shared__ __align__(16) half_t sxB[RROWS][LDSW];
    __shared__ __align__(16) half_t syB[RROWS][LDSW];

    const int tid    = threadIdx.x;
    const int tr0    = blockIdx.y * TILE;
    const int tc0    = blockIdx.x * TILE;
    const int plane0 = blockIdx.z;            // planes plane0, +32, +64

    const int q   = tid & 15;
    const int cb  = 4 * q;
    const int rg  = tid >> 4;                 // 0..15

    float mse_acc = 0.0f, ssim_acc = 0.0f;

    float4 hxA[2], hyA[2];                    // held A prefetch (next tile)
    bool   havePF = false;

    for (int t = 0; t < 3; ++t) {
        const int plane = plane0 + 32 * t;
        const float* __restrict__ xp = X + (size_t)plane * (PLANE_H * PLANE_W);
        const float* __restrict__ yp = Y + (size_t)plane * (PLANE_H * PLANE_W);

        // ---- write region A (from prefetch regs if available) ----
        if (!havePF) {
            // prologue: inline stage A (612 quads)
            for (int i = tid; i < RQUADS; i += 256) {
                const int r  = i / 18;
                const int hq = i - r * 18;
                const int gr = tr0 - 1 + r;
                const int gc = tc0 - 4 + 4 * hq;
                float4 vx = make_float4(0.f, 0.f, 0.f, 0.f);
                float4 vy = make_float4(0.f, 0.f, 0.f, 0.f);
                if ((unsigned)gr < PLANE_H && (unsigned)gc < PLANE_W) {
                    const size_t g = (size_t)gr * PLANE_W + (size_t)gc;
                    vx = *(const float4*)(xp + g);
                    vy = *(const float4*)(yp + g);
                }
                if (r >= 1 && hq >= 1 && hq <= 16) {
                    const float d0 = vx.x - vy.x, d1 = vx.y - vy.y;
                    const float d2 = vx.z - vy.z, d3 = vx.w - vy.w;
                    mse_acc += d0 * d0 + d1 * d1 + d2 * d2 + d3 * d3;
                }
                stage_write(sxA, syA, r, hq, vx, vy);
            }
        } else {
#pragma unroll
            for (int u = 0; u < 2; ++u) {
                const int i  = tid + 256 * u;
                const int r  = i / 18;           // 0..28
                const int hq = i - r * 18;
                if (r >= 1 && hq >= 1 && hq <= 16) {
                    const float d0 = hxA[u].x - hyA[u].x, d1 = hxA[u].y - hyA[u].y;
                    const float d2 = hxA[u].z - hyA[u].z, d3 = hxA[u].w - hyA[u].w;
                    mse_acc += d0 * d0 + d1 * d1 + d2 * d2 + d3 * d3;
                }
                stage_write(sxA, syA, r, hq, hxA[u], hyA[u]);
            }
            const int i = tid + PFQ;             // tail 512..611
            if (i < RQUADS) {
                const int r  = i / 18;           // 28..33
                const int hq = i - r * 18;
                const int gr = tr0 - 1 + r;
                const int gc = tc0 - 4 + 4 * hq;
                float4 vx = make_float4(0.f, 0.f, 0.f, 0.f);
                float4 vy = make_float4(0.f, 0.f, 0.f, 0.f);
                if ((unsigned)gr < PLANE_H && (unsigned)gc < PLANE_W) {
                    const size_t g = (size_t)gr * PLANE_W + (size_t)gc;
                    vx = *(const float4*)(xp + g);
                    vy = *(const float4*)(yp + g);
                }
                if (hq >= 1 && hq <= 16) {       // r>=28 => r>=1 holds
                    const float d0 = vx.x - vy.x, d1 = vx.y - vy.y;
                    const float d2 = vx.z - vy.z, d3 = vx.w - vy.w;
                    mse_acc += d0 * d0 + d1 * d1 + d2 * d2 + d3 * d3;
                }
                stage_write(sxA, syA, r, hq, vx, vy);
            }
        }

        __syncthreads();                         // A visible; vmcnt already 0

        // ---- issue region-B prefetch (flies under passA) ----
        float4 hxB[2], hyB[2];
#pragma unroll
        for (int u = 0; u < 2; ++u) {
            const int i  = tid + 256 * u;
            const int r  = i / 18;
            const int hq = i - r * 18;
            const int gr = tr0 + 31 + r;
            const int gc = tc0 - 4 + 4 * hq;
            hxB[u] = make_float4(0.f, 0.f, 0.f, 0.f);
            hyB[u] = make_float4(0.f, 0.f, 0.f, 0.f);
            if ((unsigned)gr < PLANE_H && (unsigned)gc < PLANE_W) {
                const size_t g = (size_t)gr * PLANE_W + (size_t)gc;
                hxB[u] = *(const float4*)(xp + g);
                hyB[u] = *(const float4*)(yp + g);
            }
        }
        __builtin_amdgcn_sched_barrier(0);       // pin issue above passA

        // ---- pass A: pixel rows tr0..tr0+31 ----
        ssim_pass(sxA, syA, 2 * rg, cb, ssim_acc);

        // ---- write region B (waits B prefetch here, not at a barrier) ----
#pragma unroll
        for (int u = 0; u < 2; ++u) {
            const int i  = tid + 256 * u;
            const int r  = i / 18;               // 0..28
            const int hq = i - r * 18;
            if (r >= 2 && hq >= 1 && hq <= 16) { // r<=28 => r<=32 holds
                const float d0 = hxB[u].x - hyB[u].x, d1 = hxB[u].y - hyB[u].y;
                const float d2 = hxB[u].z - hyB[u].z, d3 = hxB[u].w - hyB[u].w;
                mse_acc += d0 * d0 + d1 * d1 + d2 * d2 + d3 * d3;
            }
            stage_write(sxB, syB, r, hq, hxB[u], hyB[u]);
        }
        {
            const int i = tid + PFQ;
            if (i < RQUADS) {
                const int r  = i / 18;           // 28..33
                const int hq = i - r * 18;
                const int gr = tr0 + 31 + r;
                const int gc = tc0 - 4 + 4 * hq;
                float4 vx = make_float4(0.f, 0.f, 0.f, 0.f);
                float4 vy = make_float4(0.f, 0.f, 0.f, 0.f);
                if ((unsigned)gr < PLANE_H && (unsigned)gc < PLANE_W) {
                    const size_t g = (size_t)gr * PLANE_W + (size_t)gc;
                    vx = *(const float4*)(xp + g);
                    vy = *(const float4*)(yp + g);
                }
                if (r <= 32 && hq >= 1 && hq <= 16) {
                    const float d0 = vx.x - vy.x, d1 = vx.y - vy.y;
                    const float d2 = vx.z - vy.z, d3 = vx.w - vy.w;
                    mse_acc += d0 * d0 + d1 * d1 + d2 * d2 + d3 * d3;
                }
                stage_write(sxB, syB, r, hq, vx, vy);
            }
        }

        __syncthreads();                         // B visible; vmcnt already 0

        // ---- issue next-tile region-A prefetch (flies under passB) ----
        if (t < 2) {
            const float* __restrict__ xpn = xp + (size_t)32 * (PLANE_H * PLANE_W);
            const float* __restrict__ ypn = yp + (size_t)32 * (PLANE_H * PLANE_W);
#pragma unroll
            for (int u = 0; u < 2; ++u) {
                const int i  = tid + 256 * u;
                const int r  = i / 18;
                const int hq = i - r * 18;
                const int gr = tr0 - 1 + r;
                const int gc = tc0 - 4 + 4 * hq;
                hxA[u] = make_float4(0.f, 0.f, 0.f, 0.f);
                hyA[u] = make_float4(0.f, 0.f, 0.f, 0.f);
                if ((unsigned)gr < PLANE_H && (unsigned)gc < PLANE_W) {
                    const size_t g = (size_t)gr * PLANE_W + (size_t)gc;
                    hxA[u] = *(const float4*)(xpn + g);
                    hyA[u] = *(const float4*)(ypn + g);
                }
            }
            __builtin_amdgcn_sched_barrier(0);   // pin issue above passB
            havePF = true;
        }

        // ---- pass B: pixel rows tr0+32..tr0+63 ----
        ssim_pass(sxB, syB, 2 * rg, cb, ssim_acc);
    }

    // ---- block reduction ----
#pragma unroll
    for (int off = 32; off > 0; off >>= 1) {
        mse_acc  += __shfl_down(mse_acc, off, 64);
        ssim_acc += __shfl_down(ssim_acc, off, 64);
    }
    __shared__ float red[8];
    const int wave = tid >> 6;
    if ((tid & 63) == 0) {
        red[wave]     = mse_acc;
        red[4 + wave] = ssim_acc;
    }
    __syncthreads();
    if (tid == 0) {
        const int bid = (blockIdx.z * gridDim.y + blockIdx.y) * gridDim.x + blockIdx.x;
        part[bid]           = red[0] + red[1] + red[2] + red[3];
        part[NBLOCKS + bid] = red[4] + red[5] + red[6] + red[7];
    }
}

__global__ __launch_bounds__(256) void loss_reduce1(
    const float* __restrict__ part, float* __restrict__ part2)
{
    const int tid = threadIdx.x;
    const int i   = blockIdx.x * 256 + tid;
    float m = part[i];
    float s = part[NBLOCKS + i];
#pragma unroll
    for (int off = 32; off > 0; off >>= 1) {
        m += __shfl_down(m, off, 64);
        s += __shfl_down(s, off, 64);
    }
    __shared__ float red[8];
    const int wave = tid >> 6;
    if ((tid & 63) == 0) {
        red[wave]     = m;
        red[4 + wave] = s;
    }
    __syncthreads();
    if (tid == 0) {
        part2[blockIdx.x]       = red[0] + red[1] + red[2] + red[3];
        part2[NB1 + blockIdx.x] = red[4] + red[5] + red[6] + red[7];
    }
}

__global__ __launch_bounds__(64) void loss_final(
    const float* __restrict__ part2, float* __restrict__ out)
{
    const int tid = threadIdx.x;
    float m = 0.0f, s = 0.0f;
    if (tid < NB1) {
        m = part2[tid];
        s = part2[NB1 + tid];
    }
#pragma unroll
    for (int off = 32; off > 0; off >>= 1) {
        m += __shfl_down(m, off, 64);
        s += __shfl_down(s, off, 64);
    }
    if (tid == 0) {
        const float mse       = m * kINVN;
        const float ssim_mean = s * kINVN;
        out[0] = 0.8f * mse + 0.2f * (1.0f - ssim_mean);
    }
}

extern "C" void kernel_launch(void* const* d_in, const int* in_sizes, int n_in,
                              void* d_out, int out_size, void* d_ws, size_t ws_size,
                              hipStream_t stream)
{
    const float* x = (const float*)d_in[0];   // reconstruction
    const float* y = (const float*)d_in[1];   // target
    float* out   = (float*)d_out;
    float* part  = (float*)d_ws;              // 2*NBLOCKS floats
    float* part2 = part + 2 * NBLOCKS;        // 2*NB1 floats

    dim3 grid(PLANE_W / TILE, PLANE_H / TILE, NPLANES / 3);   // 8 x 8 x 32 = 2048
    loss_main<<<grid, 256, 0, stream>>>(x, y, part);
    loss_reduce1<<<NB1, 256, 0, stream>>>(part, part2);
    loss_final<<<1, 64, 0, stream>>>(part2, out);
}

// Round 4
// 237.467 us; speedup vs baseline: 1.1052x; 1.1052x over previous
//
#include <hip/hip_runtime.h>

// EnhancedReconstructionLoss: loss = 0.8*mean((x-y)^2) + 0.2*(1 - mean(ssim_map))
// ssim from 3x3 avg pools (stride 1, zero-pad 1, divisor always 9).
// Shapes: (32,3,512,512) fp32 -> 96 planes of 512x512.
//
// R6: f16 LDS staging, 4x4/thread. 89 us, VALUBusy 43%, HBM 28% (serialized).
// R8 FAILED: agent-scope ACQ_REL finish -> 372 us.
// R9 NEUTRAL: prefetch issued before __syncthreads -> drained by its vmcnt(0).
// R10 FAILED (127 us): reg-held prefetch spilled to scratch (WRITE_SIZE
//     0.4 -> 152 MB, FETCH +79 MB): holds crossing 2 passes + loop back-edge
//     blew the (256,8) 64-VGPR cap; allocator parked float4s in scratch.
// R11 (this): global_load_lds DMA staging (zero registers held) + counted
//     vmcnt pipeline (T3/T4-lite):
//     - f32 LDS, 2 regions (A rows tr0-1..tr0+32, B rows tr0+31..tr0+64),
//       39.2 KB -> 4 blocks/CU; kills cvt+ds_write staging VALU and all
//       f16<->f32 converts; SSIM inputs now exact f32.
//     - persistent 8x8x16=1024 blocks (exactly resident), 6 planes each.
//     - schedule/tile: vmcnt(5)|bar|passA(B flies)|bar|issueA'|vmcnt(5)|bar|
//       passB(A' flies)|bar|issueB'. Raw s_barrier; never drain vmcnt in loop.
//     - per-wave DMA span 4896 B = 5 uniform dwordx4 issues (last exec-masked)
//       -> per-wave vmcnt counting is uniform.
//     - OOB halo: per-lane global src redirected to zeroed ws buffer
//       (LDS dest must stay linear: guide m104/m173).
//     - MSE computed in-pass from f32 LDS (each pixel once, exact).

#define PLANE_H 512
#define PLANE_W 512
#define TILE    64
#define RROWS   34
#define RF      72                        // floats per region row (288 B)
#define WSPAN   4896                      // bytes per wave per region (=306*16)
#define WUNITS  306
#define NTILES  6
#define NBLOCKS 1024                      // 8*8*16
#define NB1     (NBLOCKS / 256)           // 4

static constexpr float kC1s  = 81.0f * 0.0001f;   // 81*C1
static constexpr float kC2s  = 81.0f * 0.0009f;   // 81*C2
static constexpr float kEPSs = 6561.0f * 1e-8f;   // 81^2*eps
static constexpr float kINVN = 1.0f / 25165824.0f;

typedef __attribute__((address_space(1))) const void gas_void;
typedef __attribute__((address_space(3))) void las_void;

__device__ __forceinline__ void gl_lds16(const void* g, void* l)
{
    // global -> LDS DMA, 16 B per lane; LDS dest = wave base + lane*16
    __builtin_amdgcn_global_load_lds((gas_void*)g, (las_void*)l, 16, 0, 0);
}

#define VMCNT5() asm volatile("s_waitcnt vmcnt(5)" ::: "memory")
#define VMCNT0() asm volatile("s_waitcnt vmcnt(0)" ::: "memory")
#define SBAR()   do { asm volatile("" ::: "memory");      \
                      __builtin_amdgcn_s_barrier();       \
                      asm volatile("" ::: "memory"); } while (0)

// one region pass: thread (rg = tid>>4, q = tid&15) reads region rows
// 2rg..2rg+3, window floats 4q+3..4q+8; outputs centers at region rows
// 2rg+1, 2rg+2 (j = 1,2), pixel cols tc0+4q..tc0+4q+3.  All f32.
__device__ __forceinline__ void ssim_pass(
    float (*sx)[RF], float (*sy)[RF],
    const int pr0, const int q, float& mse_acc, float& ssim_acc)
{
    float ring[3][4][4];   // [row%3][qty: x,y,xx+yy,xy][col]
#pragma unroll
    for (int j = 0; j < 4; ++j) {
        const int R = pr0 + j;
        const float* __restrict__ rx = &sx[R][0];
        const float* __restrict__ ry = &sy[R][0];
        const float2 ax = *(const float2*)&rx[4 * q + 2];   // ds_read_b64
        const float4 bx = *(const float4*)&rx[4 * q + 4];   // ds_read_b128
        const float  cx = rx[4 * q + 8];                    // ds_read_b32
        const float2 ay = *(const float2*)&ry[4 * q + 2];
        const float4 by = *(const float4*)&ry[4 * q + 4];
        const float  cy = ry[4 * q + 8];
        const float ex0 = ax.y, ex1 = bx.x, ex2 = bx.y,
                    ex3 = bx.z, ex4 = bx.w, ex5 = cx;
        const float ey0 = ay.y, ey1 = by.x, ey2 = by.y,
                    ey3 = by.z, ey4 = by.w, ey5 = cy;

        if (j == 1 || j == 2) {      // center rows: exact f32 MSE, once/pixel
            const float d0 = ex1 - ey1, d1 = ex2 - ey2;
            const float d2 = ex3 - ey3, d3 = ex4 - ey4;
            mse_acc += d0 * d0 + d1 * d1 + d2 * d2 + d3 * d3;
        }

        float (&slot)[4][4] = ring[j % 3];   // static after unroll
        {
            const float t12 = ex1 + ex2, t23 = ex2 + ex3, t34 = ex3 + ex4;
            slot[0][0] = ex0 + t12; slot[0][1] = t12 + ex3;
            slot[0][2] = t23 + ex4; slot[0][3] = t34 + ex5;
        }
        {
            const float t12 = ey1 + ey2, t23 = ey2 + ey3, t34 = ey3 + ey4;
            slot[1][0] = ey0 + t12; slot[1][1] = t12 + ey3;
            slot[1][2] = t23 + ey4; slot[1][3] = t34 + ey5;
        }
        {
            const float s0 = __builtin_fmaf(ex0, ex0, ey0 * ey0);
            const float s1 = __builtin_fmaf(ex1, ex1, ey1 * ey1);
            const float s2 = __builtin_fmaf(ex2, ex2, ey2 * ey2);
            const float s3 = __builtin_fmaf(ex3, ex3, ey3 * ey3);
            const float s4 = __builtin_fmaf(ex4, ex4, ey4 * ey4);
            const float s5 = __builtin_fmaf(ex5, ex5, ey5 * ey5);
            const float t12 = s1 + s2, t23 = s2 + s3, t34 = s3 + s4;
            slot[2][0] = s0 + t12; slot[2][1] = t12 + s3;
            slot[2][2] = t23 + s4; slot[2][3] = t34 + s5;
        }
        {
            const float p0 = ex0 * ey0, p1 = ex1 * ey1, p2 = ex2 * ey2;
            const float p3 = ex3 * ey3, p4 = ex4 * ey4, p5 = ex5 * ey5;
            const float t12 = p1 + p2, t23 = p2 + p3, t34 = p3 + p4;
            slot[3][0] = p0 + t12; slot[3][1] = t12 + p3;
            slot[3][2] = t23 + p4; slot[3][3] = t34 + p5;
        }

        if (j >= 2) {
#pragma unroll
            for (int c = 0; c < 4; ++c) {
                const float S_x = ring[0][0][c] + ring[1][0][c] + ring[2][0][c];
                const float S_y = ring[0][1][c] + ring[1][1][c] + ring[2][1][c];
                const float S_s = ring[0][2][c] + ring[1][2][c] + ring[2][2][c];
                const float S_p = ring[0][3][c] + ring[1][3][c] + ring[2][3][c];
                // scaled-domain SSIM: window sums x9 (mu x9); 81^2 cancels in
                // num/den; eps scales by 81^2.
                const float P   = S_x * S_y;
                const float Q   = __builtin_fmaf(S_x, S_x, S_y * S_y);
                const float t1  = __builtin_fmaf(2.0f, P, kC1s);
                const float t3  = __builtin_fmaf(18.0f, S_p,
                                      __builtin_fmaf(-2.0f, P, kC2s));
                const float num = t1 * t3;
                const float u2  = __builtin_fmaf(9.0f, S_s, -Q);  // >= 0 (C-S)
                const float den = __builtin_fmaf(Q + kC1s, u2 + kC2s, kEPSs);
                ssim_acc = __builtin_fmaf(num, __builtin_amdgcn_rcpf(den), ssim_acc);
            }
        }
    }
}

__global__ __launch_bounds__(256, 4) void loss_main(
    const float* __restrict__ X, const float* __restrict__ Y,
    float* __restrict__ part, const float* __restrict__ zbuf)
{
    // Region layout (linear bytes, per region): X array [0,9792), Y [9792,19584).
    // Row r = 18 quads = 288 B; float f in row <-> global col tc0-4+f.
    __shared__ __align__(16) float regA[2][RROWS][RF];
    __shared__ __align__(16) float regB[2][RROWS][RF];
    __shared__ float red[8];

    const int tid  = threadIdx.x;
    const int lane = tid & 63;
    const int wid  = tid >> 6;
    const int tr0  = blockIdx.y * TILE;
    const int tc0  = blockIdx.x * TILE;
    const int pl0  = blockIdx.z;          // planes pl0, pl0+16, ..., pl0+80

    // ---- precompute per-issue plane-relative byte offsets (-1 = OOB) ----
    // wave w copies region bytes [w*4896, (w+1)*4896): waves 0,1 -> X, 2,3 -> Y.
    const bool isY = (wid >= 2);
    int offA[5], offB[5];
#pragma unroll
    for (int i = 0; i < 5; ++i) {
        const int o   = wid * WSPAN + i * 1024 + lane * 16;
        const int oo  = isY ? (o - 2 * WSPAN) : o;
        const int qi  = oo >> 4;                 // quad index 0..611 (if active)
        const int r   = qi / 18;
        const int hq  = qi - r * 18;
        const int gc  = tc0 - 4 + 4 * hq;
        const int grA = tr0 - 1 + r;
        const int grB = tr0 + 31 + r;
        offA[i] = ((unsigned)grA < PLANE_H && (unsigned)gc < PLANE_W)
                ? (grA * (PLANE_W * 4) + gc * 4) : -1;
        offB[i] = ((unsigned)grB < PLANE_H && (unsigned)gc < PLANE_W)
                ? (grB * (PLANE_W * 4) + gc * 4) : -1;
    }

    auto issue = [&](const float* xp, const float* yp, float* reg, const int* off) {
        const char* basep = (const char*)(isY ? yp : xp);
#pragma unroll
        for (int i = 0; i < 5; ++i) {
            const int unit = i * 64 + lane;
            const int o    = wid * WSPAN + i * 1024 + lane * 16;
            const float* src = (off[i] >= 0)
                             ? (const float*)(basep + off[i])
                             : (zbuf + lane * 4);    // zero-pad source
            if (unit < WUNITS)                        // last issue: lanes < 50
                gl_lds16(src, (char*)reg + o);
        }
    };

    const int q  = tid & 15;
    const int rg = tid >> 4;                          // 0..15
    float mse_acc = 0.0f, ssim_acc = 0.0f;

    const float* xp = X + (size_t)pl0 * (PLANE_H * PLANE_W);
    const float* yp = Y + (size_t)pl0 * (PLANE_H * PLANE_W);

    // prologue: A(0) then B(0)  -> vmcnt = 10/wave (A oldest)
    issue(xp, yp, &regA[0][0][0], offA);
    issue(xp, yp, &regB[0][0][0], offB);

    for (int t = 0; t < NTILES; ++t) {
        const float* xpn = xp + (size_t)16 * (PLANE_H * PLANE_W);
        const float* ypn = yp + (size_t)16 * (PLANE_H * PLANE_W);

        VMCNT5();                 // A(t) landed (B's 5 still in flight)
        SBAR();                   // all waves' A DMAs complete
        ssim_pass(regA[0], regA[1], 2 * rg, q, mse_acc, ssim_acc);   // B flies
        SBAR();                   // all done reading A
        if (t + 1 < NTILES) {
            issue(xpn, ypn, &regA[0][0][0], offA);   // A(t+1) into region A
            VMCNT5();             // B(t) landed (A(t+1)'s 5 in flight)
        } else {
            VMCNT0();             // last tile: drain B
        }
        SBAR();                   // all waves' B DMAs complete
        ssim_pass(regB[0], regB[1], 2 * rg, q, mse_acc, ssim_acc);   // A' flies
        SBAR();                   // all done reading B
        if (t + 1 < NTILES)
            issue(xpn, ypn, &regB[0][0][0], offB);   // B(t+1) into region B

        xp = xpn; yp = ypn;
    }

    // ---- block reduction ----
#pragma unroll
    for (int off = 32; off > 0; off >>= 1) {
        mse_acc  += __shfl_down(mse_acc, off, 64);
        ssim_acc += __shfl_down(ssim_acc, off, 64);
    }
    const int wave = tid >> 6;
    if ((tid & 63) == 0) {
        red[wave]     = mse_acc;
        red[4 + wave] = ssim_acc;
    }
    __syncthreads();
    if (tid == 0) {
        const int bid = (blockIdx.z * gridDim.y + blockIdx.y) * gridDim.x + blockIdx.x;
        part[bid]           = red[0] + red[1] + red[2] + red[3];
        part[NBLOCKS + bid] = red[4] + red[5] + red[6] + red[7];
    }
}

__global__ __launch_bounds__(256) void loss_reduce1(
    const float* __restrict__ part, float* __restrict__ part2)
{
    const int tid = threadIdx.x;
    const int i   = blockIdx.x * 256 + tid;
    float m = part[i];
    float s = part[NBLOCKS + i];
#pragma unroll
    for (int off = 32; off > 0; off >>= 1) {
        m += __shfl_down(m, off, 64);
        s += __shfl_down(s, off, 64);
    }
    __shared__ float red[8];
    const int wave = tid >> 6;
    if ((tid & 63) == 0) {
        red[wave]     = m;
        red[4 + wave] = s;
    }
    __syncthreads();
    if (tid == 0) {
        part2[blockIdx.x]       = red[0] + red[1] + red[2] + red[3];
        part2[NB1 + blockIdx.x] = red[4] + red[5] + red[6] + red[7];
    }
}

__global__ __launch_bounds__(64) void loss_final(
    const float* __restrict__ part2, float* __restrict__ out)
{
    const int tid = threadIdx.x;
    float m = 0.0f, s = 0.0f;
    if (tid < NB1) {
        m = part2[tid];
        s = part2[NB1 + tid];
    }
#pragma unroll
    for (int off = 32; off > 0; off >>= 1) {
        m += __shfl_down(m, off, 64);
        s += __shfl_down(s, off, 64);
    }
    if (tid == 0) {
        const float mse       = m * kINVN;
        const float ssim_mean = s * kINVN;
        out[0] = 0.8f * mse + 0.2f * (1.0f - ssim_mean);
    }
}

extern "C" void kernel_launch(void* const* d_in, const int* in_sizes, int n_in,
                              void* d_out, int out_size, void* d_ws, size_t ws_size,
                              hipStream_t stream)
{
    const float* x = (const float*)d_in[0];   // reconstruction
    const float* y = (const float*)d_in[1];   // target
    float* out   = (float*)d_out;
    float* part  = (float*)d_ws;                       // 2*NBLOCKS floats (8 KB)
    float* part2 = part + 2 * NBLOCKS;                 // 2*NB1 floats
    float* zbuf  = (float*)((char*)d_ws + 16384);      // 1 KB zero source

    hipMemsetAsync(zbuf, 0, 1024, stream);             // zero-pad source

    dim3 grid(PLANE_W / TILE, PLANE_H / TILE, 16);     // 8 x 8 x 16 = 1024
    loss_main<<<grid, 256, 0, stream>>>(x, y, part, zbuf);
    loss_reduce1<<<NB1, 256, 0, stream>>>(part, part2);
    loss_final<<<1, 64, 0, stream>>>(part2, out);
}

// Round 6
// 230.459 us; speedup vs baseline: 1.1388x; 1.0304x over previous
//
#include <hip/hip_runtime.h>

// EnhancedReconstructionLoss: loss = 0.8*mean((x-y)^2) + 0.2*(1 - mean(ssim_map))
// ssim from 3x3 avg pools (stride 1, zero-pad 1, divisor always 9).
// Shapes: (32,3,512,512) fp32 -> 96 planes of 512x512.
//
// R6: f16 LDS staging. 89 us; VALU 43% / HBM 28% serialized phases.
// R8 FAILED: agent-scope ACQ_REL finish -> 372 us.
// R10 FAILED: reg-held prefetch -> scratch spill (WRITE_SIZE 152 MB), 127 us.
// R11 FAILED (100 us): f32 global_load_lds pipeline. Overlap worked but:
//     39 KB LDS -> 4 blocks/CU (occ 38%), lockstep vmcnt+barrier stalls whole
//     CU; 288 B row stride -> 4-way ds_read conflicts (and linear-DMA dest
//     forbids padding); scattered persistent blocks lost L2 halo hits.
// R12 (infra failure, resubmitted here): NO LDS. The only reuse is the 3x3
//     halo (1.16x) - L1/L2 absorb it (guide common-mistake #7: stage only
//     when data doesn't cache-fit). Each thread: own 4x4 patch from global,
//     per row 1 aligned float4 + 2 halo dwords per array, clamp+mask for
//     zero-pad. No barriers, no staging VALU, no conversions, no bank
//     conflicts; waves independent -> latency hidden by occupancy
//     (launch_bounds(256,6) caps VGPR at 84). Vertical halo reuse is
//     intra-wave -> L1; horizontal crosses tiles -> L2.

#define PLANE_H 512
#define PLANE_W 512
#define NPLANES 96
#define TILE    64
#define NBLOCKS ((PLANE_W / TILE) * (PLANE_H / TILE) * NPLANES)   // 6144
#define NB1     (NBLOCKS / 256)     // 24

static constexpr float kC1s  = 81.0f * 0.0001f;   // 81*C1
static constexpr float kC2s  = 81.0f * 0.0009f;   // 81*C2
static constexpr float kEPSs = 6561.0f * 1e-8f;   // 81^2*eps
static constexpr float kINVN = 1.0f / 25165824.0f;

__global__ __launch_bounds__(256, 6) void loss_main(
    const float* __restrict__ X, const float* __restrict__ Y,
    float* __restrict__ part)
{
    const int tid   = threadIdx.x;
    const int q     = tid & 15;          // col-group within tile
    const int rg    = tid >> 4;          // row-group 0..15
    const int tr0   = blockIdx.y * TILE;
    const int tc0   = blockIdx.x * TILE;
    const int plane = blockIdx.z;

    const int pr0 = tr0 + 4 * rg;        // output rows pr0..pr0+3
    const int pc0 = tc0 + 4 * q;         // output cols pc0..pc0+3

    const float* __restrict__ xp = X + (size_t)plane * (PLANE_H * PLANE_W);
    const float* __restrict__ yp = Y + (size_t)plane * (PLANE_H * PLANE_W);

    // halo columns, clamped for safe addressing; validity flags for zero-pad
    const int  cl   = (pc0 > 0) ? pc0 - 1 : 0;
    const int  cr   = (pc0 + 4 < PLANE_W) ? pc0 + 4 : PLANE_W - 1;
    const bool lok  = (pc0 > 0);
    const bool rok2 = (pc0 + 4 < PLANE_W);

    float mse_acc = 0.0f, ssim_acc = 0.0f;

    // ring of horizontal window sums for 3 consecutive rows
    float ring[3][4][4];   // [row%3][qty: x,y,xx+yy,xy][col]

#pragma unroll
    for (int j = 0; j < 6; ++j) {
        const int  gr  = pr0 - 1 + j;
        const int  grc = (gr < 0) ? 0 : ((gr > PLANE_H - 1) ? PLANE_H - 1 : gr);
        const bool rok = ((unsigned)gr < PLANE_H);
        const size_t ro = (size_t)grc * PLANE_W;

        const float4 vx = *(const float4*)(xp + ro + pc0);
        const float4 vy = *(const float4*)(yp + ro + pc0);
        const float  xlr = xp[ro + cl], xrr = xp[ro + cr];
        const float  ylr = yp[ro + cl], yrr = yp[ro + cr];

        // zero-pad masking
        const float ex0 = (rok && lok)  ? xlr  : 0.f;
        const float ex1 = rok ? vx.x : 0.f;
        const float ex2 = rok ? vx.y : 0.f;
        const float ex3 = rok ? vx.z : 0.f;
        const float ex4 = rok ? vx.w : 0.f;
        const float ex5 = (rok && rok2) ? xrr  : 0.f;
        const float ey0 = (rok && lok)  ? ylr  : 0.f;
        const float ey1 = rok ? vy.x : 0.f;
        const float ey2 = rok ? vy.y : 0.f;
        const float ey3 = rok ? vy.z : 0.f;
        const float ey4 = rok ? vy.w : 0.f;
        const float ey5 = (rok && rok2) ? yrr  : 0.f;

        // center rows (j=1..4 are rows pr0..pr0+3, always in-plane):
        // exact f32 MSE, each pixel exactly once
        if (j >= 1 && j <= 4) {
            const float d0 = ex1 - ey1, d1 = ex2 - ey2;
            const float d2 = ex3 - ey3, d3 = ex4 - ey4;
            mse_acc += d0 * d0 + d1 * d1 + d2 * d2 + d3 * d3;
        }

        float (&slot)[4][4] = ring[j % 3];   // static index after unroll
        {
            const float t12 = ex1 + ex2, t23 = ex2 + ex3, t34 = ex3 + ex4;
            slot[0][0] = ex0 + t12; slot[0][1] = t12 + ex3;
            slot[0][2] = t23 + ex4; slot[0][3] = t34 + ex5;
        }
        {
            const float t12 = ey1 + ey2, t23 = ey2 + ey3, t34 = ey3 + ey4;
            slot[1][0] = ey0 + t12; slot[1][1] = t12 + ey3;
            slot[1][2] = t23 + ey4; slot[1][3] = t34 + ey5;
        }
        {
            const float s0 = __builtin_fmaf(ex0, ex0, ey0 * ey0);
            const float s1 = __builtin_fmaf(ex1, ex1, ey1 * ey1);
            const float s2 = __builtin_fmaf(ex2, ex2, ey2 * ey2);
            const float s3 = __builtin_fmaf(ex3, ex3, ey3 * ey3);
            const float s4 = __builtin_fmaf(ex4, ex4, ey4 * ey4);
            const float s5 = __builtin_fmaf(ex5, ex5, ey5 * ey5);
            const float t12 = s1 + s2, t23 = s2 + s3, t34 = s3 + s4;
            slot[2][0] = s0 + t12; slot[2][1] = t12 + s3;
            slot[2][2] = t23 + s4; slot[2][3] = t34 + s5;
        }
        {
            const float p0 = ex0 * ey0, p1 = ex1 * ey1, p2 = ex2 * ey2;
            const float p3 = ex3 * ey3, p4 = ex4 * ey4, p5 = ex5 * ey5;
            const float t12 = p1 + p2, t23 = p2 + p3, t34 = p3 + p4;
            slot[3][0] = p0 + t12; slot[3][1] = t12 + p3;
            slot[3][2] = t23 + p4; slot[3][3] = t34 + p5;
        }

        if (j >= 2) {      // output row pr0 + j - 2
#pragma unroll
            for (int c = 0; c < 4; ++c) {
                const float S_x = ring[0][0][c] + ring[1][0][c] + ring[2][0][c];
                const float S_y = ring[0][1][c] + ring[1][1][c] + ring[2][1][c];
                const float S_s = ring[0][2][c] + ring[1][2][c] + ring[2][2][c];
                const float S_p = ring[0][3][c] + ring[1][3][c] + ring[2][3][c];
                // scaled-domain SSIM: window sums x9 (mu x9); 81^2 cancels in
                // num/den; eps scales by 81^2.
                const float P   = S_x * S_y;
                const float Q   = __builtin_fmaf(S_x, S_x, S_y * S_y);
                const float t1  = __builtin_fmaf(2.0f, P, kC1s);
                const float t3  = __builtin_fmaf(18.0f, S_p,
                                      __builtin_fmaf(-2.0f, P, kC2s));
                const float num = t1 * t3;
                const float u2  = __builtin_fmaf(9.0f, S_s, -Q);  // >= 0 (C-S)
                const float den = __builtin_fmaf(Q + kC1s, u2 + kC2s, kEPSs);
                ssim_acc = __builtin_fmaf(num, __builtin_amdgcn_rcpf(den), ssim_acc);
            }
        }
    }

    // ---- block reduction ----
#pragma unroll
    for (int off = 32; off > 0; off >>= 1) {
        mse_acc  += __shfl_down(mse_acc, off, 64);
        ssim_acc += __shfl_down(ssim_acc, off, 64);
    }
    __shared__ float red[8];
    const int wave = tid >> 6;
    if ((tid & 63) == 0) {
        red[wave]     = mse_acc;
        red[4 + wave] = ssim_acc;
    }
    __syncthreads();
    if (tid == 0) {
        const int bid = (blockIdx.z * gridDim.y + blockIdx.y) * gridDim.x + blockIdx.x;
        part[bid]           = red[0] + red[1] + red[2] + red[3];
        part[NBLOCKS + bid] = red[4] + red[5] + red[6] + red[7];
    }
}

__global__ __launch_bounds__(256) void loss_reduce1(
    const float* __restrict__ part, float* __restrict__ part2)
{
    const int tid = threadIdx.x;
    const int i   = blockIdx.x * 256 + tid;
    float m = part[i];
    float s = part[NBLOCKS + i];
#pragma unroll
    for (int off = 32; off > 0; off >>= 1) {
        m += __shfl_down(m, off, 64);
        s += __shfl_down(s, off, 64);
    }
    __shared__ float red[8];
    const int wave = tid >> 6;
    if ((tid & 63) == 0) {
        red[wave]     = m;
        red[4 + wave] = s;
    }
    __syncthreads();
    if (tid == 0) {
        part2[blockIdx.x]       = red[0] + red[1] + red[2] + red[3];
        part2[NB1 + blockIdx.x] = red[4] + red[5] + red[6] + red[7];
    }
}

__global__ __launch_bounds__(64) void loss_final(
    const float* __restrict__ part2, float* __restrict__ out)
{
    const int tid = threadIdx.x;
    float m = 0.0f, s = 0.0f;
    if (tid < NB1) {
        m = part2[tid];
        s = part2[NB1 + tid];
    }
#pragma unroll
    for (int off = 32; off > 0; off >>= 1) {
        m += __shfl_down(m, off, 64);
        s += __shfl_down(s, off, 64);
    }
    if (tid == 0) {
        const float mse       = m * kINVN;
        const float ssim_mean = s * kINVN;
        out[0] = 0.8f * mse + 0.2f * (1.0f - ssim_mean);
    }
}

extern "C" void kernel_launch(void* const* d_in, const int* in_sizes, int n_in,
                              void* d_out, int out_size, void* d_ws, size_t ws_size,
                              hipStream_t stream)
{
    const float* x = (const float*)d_in[0];   // reconstruction
    const float* y = (const float*)d_in[1];   // target
    float* out   = (float*)d_out;
    float* part  = (float*)d_ws;              // 2*NBLOCKS floats
    float* part2 = part + 2 * NBLOCKS;        // 2*NB1 floats

    dim3 grid(PLANE_W / TILE, PLANE_H / TILE, NPLANES);   // 8 x 8 x 96 = 6144
    loss_main<<<grid, 256, 0, stream>>>(x, y, part);
    loss_reduce1<<<NB1, 256, 0, stream>>>(part, part2);
    loss_final<<<1, 64, 0, stream>>>(part2, out);
}